// Round 1
// baseline (1084.876 us; speedup 1.0000x reference)
//
#include <hip/hip_runtime.h>
#include <math.h>

// DeepGCN layer, fp32 baseline.
// Pipeline:
//   1. CSR-by-dst build: count in-degrees (int atomics), exclusive scan, bucket fill.
//   2. h = gelu(LN1(node_feat))                       [k_ln1_gelu]
//   3. hW = h @ W_conv                                [k_gemm_conv, f-tile in LDS]
//   4. agg[d] = dinv[d]*(sum_e dinv[s]*hW[s] + dinv[d]*hW[d])   [k_gather, CSR]
//   5. conv = nf + agg + b_conv; f = LN2(conv);
//      t = gelu(f@W1+b1); f2 = gelu(t@W2+b2); out = nf + f2     [k_ffn fused, t in LDS]

__device__ __forceinline__ float gelu_f(float x){
  return 0.5f*x*(1.0f + erff(x*0.70710678118654752440f));
}

__device__ __forceinline__ float wave_reduce_sum(float v){
  #pragma unroll
  for (int off = 32; off > 0; off >>= 1) v += __shfl_xor(v, off, 64);
  return v;
}

// ---------------- graph prep ----------------
__global__ void k_init(int* incount, int N){
  int n = blockIdx.x*blockDim.x + threadIdx.x;
  if (n < N) incount[n] = 0;
}

__global__ void k_count(const int* __restrict__ ei, int* incount, int E){
  int e = blockIdx.x*blockDim.x + threadIdx.x;
  if (e < E) atomicAdd(&incount[ei[E + e]], 1);
}

__global__ void k_dinv(const int* __restrict__ incount, float* dinv, int N){
  int n = blockIdx.x*blockDim.x + threadIdx.x;
  if (n < N) dinv[n] = rsqrtf((float)incount[n] + 1.0f);  // +1 self-loop
}

// inclusive scan per 1024-chunk; chunk totals to blkSums
__global__ void k_scanA(const int* __restrict__ incount, int* row_incl, int* blkSums, int N){
  __shared__ int sh[1024];
  int t = threadIdx.x;
  int n = blockIdx.x*1024 + t;
  int v = (n < N) ? incount[n] : 0;
  sh[t] = v; __syncthreads();
  for (int off = 1; off < 1024; off <<= 1){
    int x = (t >= off) ? sh[t-off] : 0;
    __syncthreads();
    sh[t] += x;
    __syncthreads();
  }
  if (n < N) row_incl[n] = sh[t];
  if (t == 1023) blkSums[blockIdx.x] = sh[1023];
}

// exclusive scan of block sums (nb <= 128 for N=100k)
__global__ void k_scanB(const int* __restrict__ blkSums, int* blkOff, int nb){
  __shared__ int sh[128];
  int t = threadIdx.x;
  int v = (t < nb) ? blkSums[t] : 0;
  sh[t] = v; __syncthreads();
  for (int off = 1; off < 128; off <<= 1){
    int x = (t >= off) ? sh[t-off] : 0;
    __syncthreads();
    sh[t] += x;
    __syncthreads();
  }
  if (t < nb) blkOff[t] = sh[t] - v;
}

// inclusive -> exclusive + chunk offset; init cursor
__global__ void k_scanC(const int* __restrict__ incount, const int* __restrict__ blkOff,
                        int* row_start, int* cursor, int N){
  int n = blockIdx.x*blockDim.x + threadIdx.x;
  if (n < N){
    int rs = row_start[n] - incount[n] + blkOff[n >> 10];
    row_start[n] = rs;
    cursor[n] = rs;
  }
}

__global__ void k_fill(const int* __restrict__ ei, int* cursor, int* eSrc, int E){
  int e = blockIdx.x*blockDim.x + threadIdx.x;
  if (e < E){
    int s = ei[e], d = ei[E + e];
    int pos = atomicAdd(&cursor[d], 1);
    eSrc[pos] = s;
  }
}

// ---------------- h = gelu(LN1(x)) ----------------
__global__ void k_ln1_gelu(const float* __restrict__ nf, const float* __restrict__ g,
                           const float* __restrict__ b, float* __restrict__ h, int N){
  int wv = threadIdx.x >> 6, l = threadIdx.x & 63;
  int node = blockIdx.x*4 + wv;
  if (node >= N) return;
  const float* x = nf + (size_t)node*128;
  float x0 = x[l], x1 = x[l+64];
  float mu = wave_reduce_sum(x0 + x1) * 0.0078125f;
  float d0 = x0 - mu, d1 = x1 - mu;
  float var = wave_reduce_sum(d0*d0 + d1*d1) * 0.0078125f;
  float rs = rsqrtf(var + 1e-5f);
  float y0 = d0*rs*g[l]    + b[l];
  float y1 = d1*rs*g[l+64] + b[l+64];
  float* ho = h + (size_t)node*128;
  ho[l]    = gelu_f(y0);
  ho[l+64] = gelu_f(y1);
}

// ---------------- hW = h @ Wc  (32 nodes/block, 4x4 microtile) ----------------
__global__ __launch_bounds__(256) void k_gemm_conv(const float* __restrict__ h,
    const float* __restrict__ Wc, float* __restrict__ hW, int N){
  __shared__ float f_s[32][129];   // pad 129: 8 tr-groups hit distinct banks
  int t = threadIdx.x;
  int nb = blockIdx.x*32;
  #pragma unroll
  for (int p = 0; p < 16; p++){
    int m = p*2 + (t >> 7), k = t & 127;
    int node = nb + m;
    f_s[m][k] = (node < N) ? h[(size_t)node*128 + k] : 0.0f;
  }
  __syncthreads();
  int tr = t >> 5, tc = t & 31;
  int m0 = tr*4, j0 = tc*4;
  float acc[4][4];
  #pragma unroll
  for (int r = 0; r < 4; r++)
    #pragma unroll
    for (int c = 0; c < 4; c++) acc[r][c] = 0.0f;

  #pragma unroll 4
  for (int k = 0; k < 128; k++){
    float4 w = *(const float4*)&Wc[k*128 + j0];   // L2-resident, same across blocks
    float f0 = f_s[m0+0][k], f1 = f_s[m0+1][k], f2 = f_s[m0+2][k], f3 = f_s[m0+3][k];
    acc[0][0] += f0*w.x; acc[0][1] += f0*w.y; acc[0][2] += f0*w.z; acc[0][3] += f0*w.w;
    acc[1][0] += f1*w.x; acc[1][1] += f1*w.y; acc[1][2] += f1*w.z; acc[1][3] += f1*w.w;
    acc[2][0] += f2*w.x; acc[2][1] += f2*w.y; acc[2][2] += f2*w.z; acc[2][3] += f2*w.w;
    acc[3][0] += f3*w.x; acc[3][1] += f3*w.y; acc[3][2] += f3*w.z; acc[3][3] += f3*w.w;
  }
  #pragma unroll
  for (int r = 0; r < 4; r++){
    int node = nb + m0 + r;
    if (node < N){
      float4 o = make_float4(acc[r][0], acc[r][1], acc[r][2], acc[r][3]);
      *(float4*)&hW[(size_t)node*128 + j0] = o;
    }
  }
}

// ---------------- CSR gather: agg ----------------
__global__ void k_gather(const float* __restrict__ hW, const int* __restrict__ eSrc,
                         const int* __restrict__ row_start, const int* __restrict__ incount,
                         const float* __restrict__ dinv, float* __restrict__ agg, int N){
  int t = threadIdx.x;
  int node = blockIdx.x*2 + (t >> 7);
  int i = t & 127;
  if (node >= N) return;
  float dn = dinv[node];
  float sum = dn * hW[(size_t)node*128 + i];          // self-loop term
  int start = row_start[node];
  int cnt   = incount[node];
  for (int e = 0; e < cnt; e++){
    int s = eSrc[start + e];
    sum += dinv[s] * hW[(size_t)s*128 + i];
  }
  agg[(size_t)node*128 + i] = dn * sum;
}

// ---------------- fused FFN ----------------
#define MT 16
__global__ __launch_bounds__(256) void k_ffn(
    const float* __restrict__ nf, const float* __restrict__ agg,
    const float* __restrict__ bc, const float* __restrict__ g2, const float* __restrict__ bl2,
    const float* __restrict__ W1, const float* __restrict__ b1,
    const float* __restrict__ W2, const float* __restrict__ b2,
    float* __restrict__ out, int N)
{
  __shared__ float f_s[MT][132];   // 132: rows stay 16B-aligned for float4
  __shared__ float t_s[MT][516];
  int t = threadIdx.x;
  int nb = blockIdx.x*MT;

  // conv_feat = nf + agg + b_conv
  #pragma unroll
  for (int p = 0; p < 8; p++){
    int idx = p*256 + t;
    int m = idx >> 7, k = idx & 127;
    int node = nb + m;
    f_s[m][k] = (node < N) ? (nf[(size_t)node*128 + k] + agg[(size_t)node*128 + k] + bc[k]) : 0.0f;
  }
  __syncthreads();

  // LN2 in-place (one wave handles 4 nodes; lanes touch only their own slots)
  {
    int wv = t >> 6, l = t & 63;
    #pragma unroll
    for (int q = 0; q < 4; q++){
      int m = wv*4 + q;
      float x0 = f_s[m][l], x1 = f_s[m][l+64];
      float mu = wave_reduce_sum(x0 + x1) * 0.0078125f;
      float d0 = x0 - mu, d1 = x1 - mu;
      float var = wave_reduce_sum(d0*d0 + d1*d1) * 0.0078125f;
      float rs = rsqrtf(var + 1e-5f);
      f_s[m][l]    = d0*rs*g2[l]    + bl2[l];
      f_s[m][l+64] = d1*rs*g2[l+64] + bl2[l+64];
    }
  }
  __syncthreads();

  // stage 1: t = gelu(f @ W1 + b1); thread t owns columns {t, t+256}
  {
    float acc0[MT], acc1[MT];
    #pragma unroll
    for (int m = 0; m < MT; m++){ acc0[m] = 0.f; acc1[m] = 0.f; }
    for (int k = 0; k < 128; k += 4){
      float w0[4], w1[4];
      #pragma unroll
      for (int kk = 0; kk < 4; kk++){
        w0[kk] = W1[(size_t)(k+kk)*512 + t];
        w1[kk] = W1[(size_t)(k+kk)*512 + t + 256];
      }
      #pragma unroll
      for (int m = 0; m < MT; m++){
        float4 f = *(const float4*)&f_s[m][k];  // broadcast read
        acc0[m] += f.x*w0[0] + f.y*w0[1] + f.z*w0[2] + f.w*w0[3];
        acc1[m] += f.x*w1[0] + f.y*w1[1] + f.z*w1[2] + f.w*w1[3];
      }
    }
    float bv0 = b1[t], bv1 = b1[t + 256];
    #pragma unroll
    for (int m = 0; m < MT; m++){
      t_s[m][t]       = gelu_f(acc0[m] + bv0);
      t_s[m][t + 256] = gelu_f(acc1[m] + bv1);
    }
  }
  __syncthreads();

  // stage 2: f2 = gelu(t @ W2 + b2); out = nf + f2. Two 128-thread groups x 8 nodes.
  {
    int g = t >> 7, i = t & 127;
    float acc2[8];
    #pragma unroll
    for (int mm = 0; mm < 8; mm++) acc2[mm] = 0.f;
    for (int k2 = 0; k2 < 512; k2 += 4){
      float w2[4];
      #pragma unroll
      for (int kk = 0; kk < 4; kk++) w2[kk] = W2[(size_t)(k2+kk)*128 + i];
      #pragma unroll
      for (int mm = 0; mm < 8; mm++){
        float4 tv = *(const float4*)&t_s[g*8 + mm][k2];
        acc2[mm] += tv.x*w2[0] + tv.y*w2[1] + tv.z*w2[2] + tv.w*w2[3];
      }
    }
    float bv = b2[i];
    #pragma unroll
    for (int mm = 0; mm < 8; mm++){
      int node = nb + g*8 + mm;
      if (node < N)
        out[(size_t)node*128 + i] = nf[(size_t)node*128 + i] + gelu_f(acc2[mm] + bv);
    }
  }
}

extern "C" void kernel_launch(void* const* d_in, const int* in_sizes, int n_in,
                              void* d_out, int out_size, void* d_ws, size_t ws_size,
                              hipStream_t stream) {
  const float* nf   = (const float*)d_in[0];
  const int*   ei   = (const int*)  d_in[1];
  const float* ln1g = (const float*)d_in[3];
  const float* ln1b = (const float*)d_in[4];
  const float* Wc   = (const float*)d_in[5];
  const float* bc   = (const float*)d_in[6];
  const float* ln2g = (const float*)d_in[7];
  const float* ln2b = (const float*)d_in[8];
  const float* W1   = (const float*)d_in[9];
  const float* b1   = (const float*)d_in[10];
  const float* W2   = (const float*)d_in[11];
  const float* b2   = (const float*)d_in[12];
  float* out = (float*)d_out;

  int N = in_sizes[0] / 128;
  int E = in_sizes[1] / 2;

  char* ws = (char*)d_ws;
  size_t nfeat = (size_t)N * 128;
  float* h    = (float*)ws;                 // [N,128]; reused as agg after gemm_conv
  float* hW   = (float*)(ws + nfeat*4);     // [N,128]
  float* agg  = h;
  char* p = ws + nfeat*8;
  int*   incount   = (int*)p;   p += (size_t)N*4;
  float* dinv      = (float*)p; p += (size_t)N*4;
  int*   row_start = (int*)p;   p += (size_t)N*4;
  int*   cursor    = (int*)p;   p += (size_t)N*4;
  int*   eSrc      = (int*)p;   p += (size_t)E*4;
  int*   blkSums   = (int*)p;   p += 512;
  int*   blkOff    = (int*)p;

  int SB = (N + 1023) / 1024;   // <=128 for N=100k

  k_init <<<(N+255)/256, 256, 0, stream>>>(incount, N);
  k_count<<<(E+255)/256, 256, 0, stream>>>(ei, incount, E);
  k_dinv <<<(N+255)/256, 256, 0, stream>>>(incount, dinv, N);
  k_scanA<<<SB, 1024, 0, stream>>>(incount, row_start, blkSums, N);
  k_scanB<<<1, 128, 0, stream>>>(blkSums, blkOff, SB);
  k_scanC<<<(N+255)/256, 256, 0, stream>>>(incount, blkOff, row_start, cursor, N);
  k_fill <<<(E+255)/256, 256, 0, stream>>>(ei, cursor, eSrc, E);

  k_ln1_gelu <<<(N+3)/4, 256, 0, stream>>>(nf, ln1g, ln1b, h, N);
  k_gemm_conv<<<(N+31)/32, 256, 0, stream>>>(h, Wc, hW, N);
  k_gather   <<<(N+1)/2, 256, 0, stream>>>(hW, eSrc, row_start, incount, dinv, agg, N);
  k_ffn      <<<(N+MT-1)/MT, 256, 0, stream>>>(nf, agg, bc, ln2g, ln2b, W1, b1, W2, b2, out, N);
}

// Round 2
// 493.204 us; speedup vs baseline: 2.1997x; 2.1997x over previous
//
#include <hip/hip_runtime.h>
#include <math.h>

// DeepGCN layer, bf16-MFMA version.
//   prep:   CSR-by-dst (count/scan/fill) — unchanged from round 1
//   pack:   W_conv, W1, W2 -> bf16 B-fragment-major for mfma_f32_16x16x32_bf16
//   k_conv: fused LN1+gelu -> LDS bf16 -> MFMA x Wc -> hW (bf16)
//   k_gather: CSR gather of bf16 hW, fp32 accumulate -> agg (fp32)
//   k_ffn:  conv_feat+LN2 -> MFMA stage1(128->512)+gelu -> LDS -> MFMA stage2(512->128)
//           -> residual epilogue
//
// MFMA 16x16x32 bf16 verified layouts (m89/m91):
//   A[m = lane&15][k = (lane>>4)*8 + j]   (short8, 8 contiguous k)
//   B[k = (lane>>4)*8 + j][n = lane&15]
//   D[m = (lane>>4)*4 + r][n = lane&15]   (float4)

typedef short   short8  __attribute__((ext_vector_type(8)));
typedef float   floatx4 __attribute__((ext_vector_type(4)));

__device__ __forceinline__ float gelu_f(float x){
  return 0.5f*x*(1.0f + erff(x*0.70710678118654752440f));
}
__device__ __forceinline__ unsigned short f2bf(float x){   // RNE
  unsigned u = __float_as_uint(x);
  u += 0x7FFFu + ((u >> 16) & 1u);
  return (unsigned short)(u >> 16);
}
__device__ __forceinline__ float wave_reduce_sum(float v){
  #pragma unroll
  for (int off = 32; off > 0; off >>= 1) v += __shfl_xor(v, off, 64);
  return v;
}

// ---------------- graph prep (unchanged) ----------------
__global__ void k_init(int* incount, int N){
  int n = blockIdx.x*blockDim.x + threadIdx.x;
  if (n < N) incount[n] = 0;
}
__global__ void k_count(const int* __restrict__ ei, int* incount, int E){
  int e = blockIdx.x*blockDim.x + threadIdx.x;
  if (e < E) atomicAdd(&incount[ei[E + e]], 1);
}
__global__ void k_dinv(const int* __restrict__ incount, float* dinv, int N){
  int n = blockIdx.x*blockDim.x + threadIdx.x;
  if (n < N) dinv[n] = rsqrtf((float)incount[n] + 1.0f);
}
__global__ void k_scanA(const int* __restrict__ incount, int* row_incl, int* blkSums, int N){
  __shared__ int sh[1024];
  int t = threadIdx.x;
  int n = blockIdx.x*1024 + t;
  int v = (n < N) ? incount[n] : 0;
  sh[t] = v; __syncthreads();
  for (int off = 1; off < 1024; off <<= 1){
    int x = (t >= off) ? sh[t-off] : 0;
    __syncthreads();
    sh[t] += x;
    __syncthreads();
  }
  if (n < N) row_incl[n] = sh[t];
  if (t == 1023) blkSums[blockIdx.x] = sh[1023];
}
__global__ void k_scanB(const int* __restrict__ blkSums, int* blkOff, int nb){
  __shared__ int sh[128];
  int t = threadIdx.x;
  int v = (t < nb) ? blkSums[t] : 0;
  sh[t] = v; __syncthreads();
  for (int off = 1; off < 128; off <<= 1){
    int x = (t >= off) ? sh[t-off] : 0;
    __syncthreads();
    sh[t] += x;
    __syncthreads();
  }
  if (t < nb) blkOff[t] = sh[t] - v;
}
__global__ void k_scanC(const int* __restrict__ incount, const int* __restrict__ blkOff,
                        int* row_start, int* cursor, int N){
  int n = blockIdx.x*blockDim.x + threadIdx.x;
  if (n < N){
    int rs = row_start[n] - incount[n] + blkOff[n >> 10];
    row_start[n] = rs;
    cursor[n] = rs;
  }
}
__global__ void k_fill(const int* __restrict__ ei, int* cursor, int* eSrc, int E){
  int e = blockIdx.x*blockDim.x + threadIdx.x;
  if (e < E){
    int s = ei[e], d = ei[E + e];
    int pos = atomicAdd(&cursor[d], 1);
    eSrc[pos] = s;
  }
}

// ---------------- weight pack: W[K][Nc] fp32 -> B-frag-major bf16 ----------------
// Wp[((tile*(K/32) + kb)*64 + lane)*8 + j] = bf16(W[kb*32 + (lane>>4)*8 + j][tile*16 + (lane&15)])
__global__ void k_pack(const float* __restrict__ W, unsigned short* __restrict__ Wp,
                       int K, int Nc){
  int nkb = K >> 5;
  int total = (Nc >> 4) * nkb * 64;
  int id = blockIdx.x*256 + threadIdx.x;
  if (id >= total) return;
  int lane = id & 63;
  int kb   = (id >> 6) % nkb;
  int tile = id / (nkb << 6);
  int col = (tile << 4) + (lane & 15);
  int k0  = (kb << 5) + ((lane >> 4) << 3);
  unsigned short v[8];
  #pragma unroll
  for (int j = 0; j < 8; j++) v[j] = f2bf(W[(size_t)(k0 + j)*Nc + col]);
  *(short8*)&Wp[(size_t)id * 8] = *(const short8*)v;
}

// ---------------- fused LN1+gelu + conv GEMM -> hW bf16 ----------------
__global__ __launch_bounds__(256) void k_conv(const float* __restrict__ nf,
    const unsigned short* __restrict__ Wcp,
    const float* __restrict__ g1, const float* __restrict__ b1g,
    unsigned short* __restrict__ hW, int N)
{
  __shared__ __align__(16) unsigned short f_s[32][136];  // stride 136: 2-way banks only
  int t = threadIdx.x, w = t >> 6, l = t & 63;
  int nb = blockIdx.x << 5;
  #pragma unroll
  for (int q = 0; q < 8; q++){
    int m = (w << 3) + q;
    int node = nb + m;
    float x0 = 0.f, x1 = 0.f;
    if (node < N){
      size_t base = (size_t)node*128;
      x0 = nf[base + l]; x1 = nf[base + l + 64];
    }
    float mu = wave_reduce_sum(x0 + x1) * 0.0078125f;
    float d0 = x0 - mu, d1 = x1 - mu;
    float var = wave_reduce_sum(d0*d0 + d1*d1) * 0.0078125f;
    float rs = rsqrtf(var + 1e-5f);
    f_s[m][l]      = f2bf(gelu_f(d0*rs*g1[l]    + b1g[l]));
    f_s[m][l + 64] = f2bf(gelu_f(d1*rs*g1[l+64] + b1g[l+64]));
  }
  __syncthreads();
  int quad = l >> 4, ln16 = l & 15;
  short8 a[2][4];
  #pragma unroll
  for (int mt = 0; mt < 2; mt++)
    #pragma unroll
    for (int kb = 0; kb < 4; kb++)
      a[mt][kb] = *(const short8*)&f_s[(mt << 4) + ln16][(kb << 5) + (quad << 3)];
  const short8* Wp8 = (const short8*)Wcp;
  #pragma unroll
  for (int nt = 0; nt < 2; nt++){
    int tile = (w << 1) + nt;
    short8 b[4];
    #pragma unroll
    for (int kb = 0; kb < 4; kb++) b[kb] = Wp8[(size_t)((tile << 2) + kb)*64 + l];
    floatx4 acc0 = {0.f,0.f,0.f,0.f}, acc1 = {0.f,0.f,0.f,0.f};
    #pragma unroll
    for (int kb = 0; kb < 4; kb++){
      acc0 = __builtin_amdgcn_mfma_f32_16x16x32_bf16(a[0][kb], b[kb], acc0, 0, 0, 0);
      acc1 = __builtin_amdgcn_mfma_f32_16x16x32_bf16(a[1][kb], b[kb], acc1, 0, 0, 0);
    }
    int col = (tile << 4) + ln16;
    #pragma unroll
    for (int r = 0; r < 4; r++){
      int n0 = nb + (quad << 2) + r;
      if (n0 < N) hW[(size_t)n0*128 + col] = f2bf(acc0[r]);
      int n1 = n0 + 16;
      if (n1 < N) hW[(size_t)n1*128 + col] = f2bf(acc1[r]);
    }
  }
}

// ---------------- CSR gather (bf16 reads, fp32 accum) ----------------
__global__ void k_gather(const unsigned short* __restrict__ hW, const int* __restrict__ eSrc,
                         const int* __restrict__ row_start, const int* __restrict__ incount,
                         const float* __restrict__ dinv, float* __restrict__ agg, int N){
  int w = threadIdx.x >> 6, l = threadIdx.x & 63;
  int node = (blockIdx.x << 2) + w;
  if (node >= N) return;
  float dn = dinv[node];
  unsigned u = *(const unsigned*)&hW[(size_t)node*128 + (l << 1)];
  float s0 = dn * __uint_as_float(u << 16);
  float s1 = dn * __uint_as_float(u & 0xFFFF0000u);
  int start = row_start[node], cnt = incount[node];
  for (int e = 0; e < cnt; e++){
    int s = eSrc[start + e];
    float ds = dinv[s];
    unsigned v = *(const unsigned*)&hW[(size_t)s*128 + (l << 1)];
    s0 += ds * __uint_as_float(v << 16);
    s1 += ds * __uint_as_float(v & 0xFFFF0000u);
  }
  float2 o; o.x = dn*s0; o.y = dn*s1;
  *(float2*)&agg[(size_t)node*128 + (l << 1)] = o;
}

// ---------------- fused FFN (MFMA) ----------------
__global__ __launch_bounds__(256) void k_ffn(
    const float* __restrict__ nf, const float* __restrict__ agg,
    const float* __restrict__ bc, const float* __restrict__ g2, const float* __restrict__ bl2,
    const unsigned short* __restrict__ W1p, const float* __restrict__ b1,
    const unsigned short* __restrict__ W2p, const float* __restrict__ b2,
    float* __restrict__ out, int N)
{
  __shared__ __align__(16) unsigned short f_s[32][136];
  __shared__ __align__(16) unsigned short t_s[32][520];  // stride 520: 2-way banks only
  int t = threadIdx.x, w = t >> 6, l = t & 63;
  int nb = blockIdx.x << 5;

  // phase A: conv_feat = nf + agg + bc; LN2 -> f_s (bf16)
  #pragma unroll
  for (int q = 0; q < 8; q++){
    int m = (w << 3) + q;
    int node = nb + m;
    float x0 = 0.f, x1 = 0.f;
    if (node < N){
      size_t base = (size_t)node*128;
      x0 = nf[base + l]      + agg[base + l]      + bc[l];
      x1 = nf[base + l + 64] + agg[base + l + 64] + bc[l + 64];
    }
    float mu = wave_reduce_sum(x0 + x1) * 0.0078125f;
    float d0 = x0 - mu, d1 = x1 - mu;
    float var = wave_reduce_sum(d0*d0 + d1*d1) * 0.0078125f;
    float rs = rsqrtf(var + 1e-5f);
    f_s[m][l]      = f2bf(d0*rs*g2[l]    + bl2[l]);
    f_s[m][l + 64] = f2bf(d1*rs*g2[l+64] + bl2[l+64]);
  }
  __syncthreads();

  int quad = l >> 4, ln16 = l & 15;

  // stage 1: t = gelu(f @ W1 + b1) -> t_s bf16. Wave w owns N-tiles [w*8, w*8+8).
  {
    short8 a[2][4];
    #pragma unroll
    for (int mt = 0; mt < 2; mt++)
      #pragma unroll
      for (int kb = 0; kb < 4; kb++)
        a[mt][kb] = *(const short8*)&f_s[(mt << 4) + ln16][(kb << 5) + (quad << 3)];
    const short8* Wp8 = (const short8*)W1p;
    #pragma unroll
    for (int nt = 0; nt < 8; nt++){
      int tile = (w << 3) + nt;
      short8 b[4];
      #pragma unroll
      for (int kb = 0; kb < 4; kb++) b[kb] = Wp8[(size_t)((tile << 2) + kb)*64 + l];
      floatx4 acc0 = {0.f,0.f,0.f,0.f}, acc1 = {0.f,0.f,0.f,0.f};
      #pragma unroll
      for (int kb = 0; kb < 4; kb++){
        acc0 = __builtin_amdgcn_mfma_f32_16x16x32_bf16(a[0][kb], b[kb], acc0, 0, 0, 0);
        acc1 = __builtin_amdgcn_mfma_f32_16x16x32_bf16(a[1][kb], b[kb], acc1, 0, 0, 0);
      }
      int col = (tile << 4) + ln16;
      float bv = b1[col];
      #pragma unroll
      for (int r = 0; r < 4; r++){
        t_s[(quad << 2) + r][col]      = f2bf(gelu_f(acc0[r] + bv));
        t_s[16 + (quad << 2) + r][col] = f2bf(gelu_f(acc1[r] + bv));
      }
    }
  }
  __syncthreads();

  // stage 2: f2 = gelu(t @ W2 + b2); out = nf + f2. Wave w owns N-tiles {2w, 2w+1}.
  {
    const short8* Wp8 = (const short8*)W2p;
    int tile0 = (w << 1), tile1 = tile0 + 1;
    floatx4 acc00 = {0.f,0.f,0.f,0.f}, acc01 = {0.f,0.f,0.f,0.f};
    floatx4 acc10 = {0.f,0.f,0.f,0.f}, acc11 = {0.f,0.f,0.f,0.f};
    for (int kb = 0; kb < 16; kb++){
      short8 a0 = *(const short8*)&t_s[ln16][(kb << 5) + (quad << 3)];
      short8 a1 = *(const short8*)&t_s[16 + ln16][(kb << 5) + (quad << 3)];
      short8 b0 = Wp8[(size_t)((tile0 << 4) + kb)*64 + l];
      short8 b1v = Wp8[(size_t)((tile1 << 4) + kb)*64 + l];
      acc00 = __builtin_amdgcn_mfma_f32_16x16x32_bf16(a0, b0,  acc00, 0, 0, 0);
      acc01 = __builtin_amdgcn_mfma_f32_16x16x32_bf16(a0, b1v, acc01, 0, 0, 0);
      acc10 = __builtin_amdgcn_mfma_f32_16x16x32_bf16(a1, b0,  acc10, 0, 0, 0);
      acc11 = __builtin_amdgcn_mfma_f32_16x16x32_bf16(a1, b1v, acc11, 0, 0, 0);
    }
    int col0 = (tile0 << 4) + ln16, col1 = (tile1 << 4) + ln16;
    float bv0 = b2[col0], bv1 = b2[col1];
    #pragma unroll
    for (int r = 0; r < 4; r++){
      int n0 = nb + (quad << 2) + r;       // mt = 0
      int n1 = n0 + 16;                    // mt = 1
      if (n0 < N){
        size_t p0 = (size_t)n0*128;
        out[p0 + col0] = nf[p0 + col0] + gelu_f(acc00[r] + bv0);
        out[p0 + col1] = nf[p0 + col1] + gelu_f(acc01[r] + bv1);
      }
      if (n1 < N){
        size_t p1 = (size_t)n1*128;
        out[p1 + col0] = nf[p1 + col0] + gelu_f(acc10[r] + bv0);
        out[p1 + col1] = nf[p1 + col1] + gelu_f(acc11[r] + bv1);
      }
    }
  }
}

extern "C" void kernel_launch(void* const* d_in, const int* in_sizes, int n_in,
                              void* d_out, int out_size, void* d_ws, size_t ws_size,
                              hipStream_t stream) {
  const float* nf   = (const float*)d_in[0];
  const int*   ei   = (const int*)  d_in[1];
  const float* ln1g = (const float*)d_in[3];
  const float* ln1b = (const float*)d_in[4];
  const float* Wc   = (const float*)d_in[5];
  const float* bc   = (const float*)d_in[6];
  const float* ln2g = (const float*)d_in[7];
  const float* ln2b = (const float*)d_in[8];
  const float* W1   = (const float*)d_in[9];
  const float* b1   = (const float*)d_in[10];
  const float* W2   = (const float*)d_in[11];
  const float* b2   = (const float*)d_in[12];
  float* out = (float*)d_out;

  int N = in_sizes[0] / 128;
  int E = in_sizes[1] / 2;

  char* ws = (char*)d_ws;
  float* agg = (float*)ws;                                   // [N,128] fp32
  unsigned short* hW = (unsigned short*)(ws + (size_t)N*128*4);  // [N,128] bf16
  char* p = ws + (size_t)N*128*4 + (size_t)N*128*2;
  // align to 16
  p = (char*)(((size_t)p + 15) & ~(size_t)15);
  int*   incount   = (int*)p;   p += (size_t)N*4;
  float* dinv      = (float*)p; p += (size_t)N*4;
  int*   row_start = (int*)p;   p += (size_t)N*4;
  int*   cursor    = (int*)p;   p += (size_t)N*4;
  int*   eSrc      = (int*)p;   p += (size_t)E*4;
  int*   blkSums   = (int*)p;   p += 512;
  int*   blkOff    = (int*)p;   p += 512;
  p = (char*)(((size_t)p + 15) & ~(size_t)15);
  unsigned short* Wcp = (unsigned short*)p; p += (size_t)8*4*64*8*2;     // 32 KB
  unsigned short* W1p = (unsigned short*)p; p += (size_t)32*4*64*8*2;    // 128 KB
  unsigned short* W2p = (unsigned short*)p; p += (size_t)8*16*64*8*2;    // 128 KB

  int SB = (N + 1023) / 1024;

  k_init <<<(N+255)/256, 256, 0, stream>>>(incount, N);
  k_count<<<(E+255)/256, 256, 0, stream>>>(ei, incount, E);
  k_dinv <<<(N+255)/256, 256, 0, stream>>>(incount, dinv, N);
  k_scanA<<<SB, 1024, 0, stream>>>(incount, row_start, blkSums, N);
  k_scanB<<<1, 128, 0, stream>>>(blkSums, blkOff, SB);
  k_scanC<<<(N+255)/256, 256, 0, stream>>>(incount, blkOff, row_start, cursor, N);
  k_fill <<<(E+255)/256, 256, 0, stream>>>(ei, cursor, eSrc, E);

  k_pack<<<8,  256, 0, stream>>>(Wc, Wcp, 128, 128);
  k_pack<<<32, 256, 0, stream>>>(W1, W1p, 128, 512);
  k_pack<<<32, 256, 0, stream>>>(W2, W2p, 512, 128);

  k_conv  <<<(N+31)/32, 256, 0, stream>>>(nf, Wcp, ln1g, ln1b, hW, N);
  k_gather<<<(N+3)/4, 256, 0, stream>>>(hW, eSrc, row_start, incount, dinv, agg, N);
  k_ffn   <<<(N+31)/32, 256, 0, stream>>>(nf, agg, bc, ln2g, ln2b, W1p, b1, W2p, b2, out, N);
}

// Round 3
// 389.856 us; speedup vs baseline: 2.7828x; 1.2651x over previous
//
#include <hip/hip_runtime.h>
#include <math.h>

// DeepGCN layer, bf16-MFMA version, round 3.
//   - fast tanh-form GELU (v_exp + v_rcp) instead of erff       [k_conv, k_ffn]
//   - k_gather: 4 edge-slots per wave (16 lanes x 16B per row), shuffle-reduce
//   - k_ffn: f_s unioned into t_s -> 33.3 KB LDS -> 4 blocks/CU
//   - shuffle-based scans; dinv folded into scanC
//
// MFMA 16x16x32 bf16 verified layouts (m89/m91):
//   A[m = lane&15][k = (lane>>4)*8 + j]   (short8)
//   B[k = (lane>>4)*8 + j][n = lane&15]
//   D[m = (lane>>4)*4 + r][n = lane&15]   (float4)

typedef short   short8  __attribute__((ext_vector_type(8)));
typedef float   floatx4 __attribute__((ext_vector_type(4)));

// tanh-form GELU: x*sigmoid(1.595769*(x+0.044715 x^3)); max abs err ~1e-3
__device__ __forceinline__ float gelu_f(float x){
  float x2 = x*x;
  float z  = x*(1.5957691216f + 0.07135481283f*x2);
  float e  = __expf(-z);
  return x * __builtin_amdgcn_rcpf(1.0f + e);
}
__device__ __forceinline__ unsigned short f2bf(float x){   // RNE
  unsigned u = __float_as_uint(x);
  u += 0x7FFFu + ((u >> 16) & 1u);
  return (unsigned short)(u >> 16);
}
__device__ __forceinline__ float bflo(unsigned u){ return __uint_as_float(u << 16); }
__device__ __forceinline__ float bfhi(unsigned u){ return __uint_as_float(u & 0xFFFF0000u); }
__device__ __forceinline__ float wave_reduce_sum(float v){
  #pragma unroll
  for (int off = 32; off > 0; off >>= 1) v += __shfl_xor(v, off, 64);
  return v;
}

// ---------------- graph prep ----------------
__global__ void k_init(int* incount, int N){
  int n = blockIdx.x*blockDim.x + threadIdx.x;
  if (n < N) incount[n] = 0;
}
__global__ void k_count(const int* __restrict__ ei, int* incount, int E){
  int e = blockIdx.x*blockDim.x + threadIdx.x;
  if (e < E) atomicAdd(&incount[ei[E + e]], 1);
}
// 256-node chunks, wave shuffle scan
__global__ void k_scanA(const int* __restrict__ incount, int* row_incl, int* blkSums, int N){
  __shared__ int wsum[4];
  int t = threadIdx.x, w = t >> 6, l = t & 63;
  int n = blockIdx.x*256 + t;
  int v = (n < N) ? incount[n] : 0;
  int x = v;
  #pragma unroll
  for (int off = 1; off < 64; off <<= 1){
    int y = __shfl_up(x, off);
    if (l >= off) x += y;
  }
  if (l == 63) wsum[w] = x;
  __syncthreads();
  if (t == 0){
    int s = 0;
    #pragma unroll
    for (int i = 0; i < 4; i++){ int c = wsum[i]; wsum[i] = s; s += c; }
  }
  __syncthreads();
  x += wsum[w];
  if (n < N) row_incl[n] = x;
  if (t == 255) blkSums[blockIdx.x] = x;
}
// scan of up to 512 block sums
__global__ void k_scanB(const int* __restrict__ blkSums, int* blkOff, int nb){
  __shared__ int wsum[8];
  int t = threadIdx.x, w = t >> 6, l = t & 63;
  int v = (t < nb) ? blkSums[t] : 0;
  int x = v;
  #pragma unroll
  for (int off = 1; off < 64; off <<= 1){
    int y = __shfl_up(x, off);
    if (l >= off) x += y;
  }
  if (l == 63) wsum[w] = x;
  __syncthreads();
  if (t == 0){
    int s = 0;
    #pragma unroll
    for (int i = 0; i < 8; i++){ int c = wsum[i]; wsum[i] = s; s += c; }
  }
  __syncthreads();
  x += wsum[w];
  if (t < nb) blkOff[t] = x - v;
}
// inclusive -> exclusive + chunk offset; init cursor; dinv
__global__ void k_scanC(const int* __restrict__ incount, const int* __restrict__ blkOff,
                        int* row_start, int* cursor, float* dinv, int N){
  int n = blockIdx.x*blockDim.x + threadIdx.x;
  if (n < N){
    int ic = incount[n];
    int rs = row_start[n] - ic + blkOff[n >> 8];
    row_start[n] = rs;
    cursor[n] = rs;
    dinv[n] = rsqrtf((float)ic + 1.0f);
  }
}
__global__ void k_fill(const int* __restrict__ ei, int* cursor, int* eSrc, int E){
  int e = blockIdx.x*blockDim.x + threadIdx.x;
  if (e < E){
    int s = ei[e], d = ei[E + e];
    int pos = atomicAdd(&cursor[d], 1);
    eSrc[pos] = s;
  }
}

// ---------------- weight pack: W[K][Nc] fp32 -> B-frag-major bf16 ----------------
__global__ void k_pack(const float* __restrict__ W, unsigned short* __restrict__ Wp,
                       int K, int Nc){
  int nkb = K >> 5;
  int total = (Nc >> 4) * nkb * 64;
  int id = blockIdx.x*256 + threadIdx.x;
  if (id >= total) return;
  int lane = id & 63;
  int kb   = (id >> 6) % nkb;
  int tile = id / (nkb << 6);
  int col = (tile << 4) + (lane & 15);
  int k0  = (kb << 5) + ((lane >> 4) << 3);
  unsigned short v[8];
  #pragma unroll
  for (int j = 0; j < 8; j++) v[j] = f2bf(W[(size_t)(k0 + j)*Nc + col]);
  *(short8*)&Wp[(size_t)id * 8] = *(const short8*)v;
}

// ---------------- fused LN1+gelu + conv GEMM -> hW bf16 ----------------
__global__ __launch_bounds__(256) void k_conv(const float* __restrict__ nf,
    const unsigned short* __restrict__ Wcp,
    const float* __restrict__ g1, const float* __restrict__ b1g,
    unsigned short* __restrict__ hW, int N)
{
  __shared__ __align__(16) unsigned short f_s[32][136];
  int t = threadIdx.x, w = t >> 6, l = t & 63;
  int nb = blockIdx.x << 5;
  #pragma unroll
  for (int q = 0; q < 8; q++){
    int m = (w << 3) + q;
    int node = nb + m;
    float x0 = 0.f, x1 = 0.f;
    if (node < N){
      size_t base = (size_t)node*128;
      x0 = nf[base + l]; x1 = nf[base + l + 64];
    }
    float mu = wave_reduce_sum(x0 + x1) * 0.0078125f;
    float d0 = x0 - mu, d1 = x1 - mu;
    float var = wave_reduce_sum(d0*d0 + d1*d1) * 0.0078125f;
    float rs = rsqrtf(var + 1e-5f);
    f_s[m][l]      = f2bf(gelu_f(d0*rs*g1[l]    + b1g[l]));
    f_s[m][l + 64] = f2bf(gelu_f(d1*rs*g1[l+64] + b1g[l+64]));
  }
  __syncthreads();
  int quad = l >> 4, ln16 = l & 15;
  short8 a[2][4];
  #pragma unroll
  for (int mt = 0; mt < 2; mt++)
    #pragma unroll
    for (int kb = 0; kb < 4; kb++)
      a[mt][kb] = *(const short8*)&f_s[(mt << 4) + ln16][(kb << 5) + (quad << 3)];
  const short8* Wp8 = (const short8*)Wcp;
  #pragma unroll
  for (int nt = 0; nt < 2; nt++){
    int tile = (w << 1) + nt;
    short8 b[4];
    #pragma unroll
    for (int kb = 0; kb < 4; kb++) b[kb] = Wp8[(size_t)((tile << 2) + kb)*64 + l];
    floatx4 acc0 = {0.f,0.f,0.f,0.f}, acc1 = {0.f,0.f,0.f,0.f};
    #pragma unroll
    for (int kb = 0; kb < 4; kb++){
      acc0 = __builtin_amdgcn_mfma_f32_16x16x32_bf16(a[0][kb], b[kb], acc0, 0, 0, 0);
      acc1 = __builtin_amdgcn_mfma_f32_16x16x32_bf16(a[1][kb], b[kb], acc1, 0, 0, 0);
    }
    int col = (tile << 4) + ln16;
    #pragma unroll
    for (int r = 0; r < 4; r++){
      int n0 = nb + (quad << 2) + r;
      if (n0 < N) hW[(size_t)n0*128 + col] = f2bf(acc0[r]);
      int n1 = n0 + 16;
      if (n1 < N) hW[(size_t)n1*128 + col] = f2bf(acc1[r]);
    }
  }
}

// ---------------- CSR gather: 4 edge-slots per wave ----------------
__global__ __launch_bounds__(256) void k_gather(const unsigned short* __restrict__ hW,
    const int* __restrict__ eSrc, const int* __restrict__ row_start,
    const int* __restrict__ incount, const float* __restrict__ dinv,
    float* __restrict__ agg, int N)
{
  int w = threadIdx.x >> 6, l = threadIdx.x & 63;
  int node = (blockIdx.x << 2) + w;
  if (node >= N) return;
  int g  = l >> 4;     // edge slot 0..3
  int li = l & 15;     // covers cols li*8 .. li*8+7
  float dn = dinv[node];
  int start = row_start[node], cnt = incount[node];
  float acc[8];
  #pragma unroll
  for (int i = 0; i < 8; i++) acc[i] = 0.f;
  // virtual edge list: e==0 -> self-loop (s=node), e>0 -> eSrc[start+e-1]
  for (int e = g; e < cnt + 1; e += 4){
    int s = (e == 0) ? node : eSrc[start + e - 1];
    float ds = dinv[s];
    uint4 v = *(const uint4*)&hW[(size_t)s*128 + (li << 3)];
    acc[0] += ds*bflo(v.x); acc[1] += ds*bfhi(v.x);
    acc[2] += ds*bflo(v.y); acc[3] += ds*bfhi(v.y);
    acc[4] += ds*bflo(v.z); acc[5] += ds*bfhi(v.z);
    acc[6] += ds*bflo(v.w); acc[7] += ds*bfhi(v.w);
  }
  #pragma unroll
  for (int i = 0; i < 8; i++){
    acc[i] += __shfl_xor(acc[i], 16);
    acc[i] += __shfl_xor(acc[i], 32);
  }
  if (l < 32){
    int h = l >> 4, li2 = l & 15;
    float4 o;
    if (h){ o = make_float4(acc[4], acc[5], acc[6], acc[7]); }
    else  { o = make_float4(acc[0], acc[1], acc[2], acc[3]); }
    o.x *= dn; o.y *= dn; o.z *= dn; o.w *= dn;
    *(float4*)&agg[(size_t)node*128 + (li2 << 3) + (h << 2)] = o;
  }
}

// ---------------- fused FFN (MFMA) ----------------
__global__ __launch_bounds__(256) void k_ffn(
    const float* __restrict__ nf, const float* __restrict__ agg,
    const float* __restrict__ bc, const float* __restrict__ g2, const float* __restrict__ bl2,
    const unsigned short* __restrict__ W1p, const float* __restrict__ b1,
    const unsigned short* __restrict__ W2p, const float* __restrict__ b2,
    float* __restrict__ out, int N)
{
  // t_s[32][520]; f_s[32][136] aliases the front (dead after A-frags load)
  __shared__ __align__(16) unsigned short u_s[32*520];
  #define F_S(r,c) u_s[(r)*136 + (c)]
  #define T_S(r,c) u_s[(r)*520 + (c)]
  int t = threadIdx.x, w = t >> 6, l = t & 63;
  int nb = blockIdx.x << 5;

  // phase A: conv_feat = nf + agg + bc; LN2 -> f_s (bf16)
  #pragma unroll
  for (int q = 0; q < 8; q++){
    int m = (w << 3) + q;
    int node = nb + m;
    float x0 = 0.f, x1 = 0.f;
    if (node < N){
      size_t base = (size_t)node*128;
      x0 = nf[base + l]      + agg[base + l]      + bc[l];
      x1 = nf[base + l + 64] + agg[base + l + 64] + bc[l + 64];
    }
    float mu = wave_reduce_sum(x0 + x1) * 0.0078125f;
    float d0 = x0 - mu, d1 = x1 - mu;
    float var = wave_reduce_sum(d0*d0 + d1*d1) * 0.0078125f;
    float rs = rsqrtf(var + 1e-5f);
    F_S(m, l)      = f2bf(d0*rs*g2[l]    + bl2[l]);
    F_S(m, l + 64) = f2bf(d1*rs*g2[l+64] + bl2[l+64]);
  }
  __syncthreads();

  int quad = l >> 4, ln16 = l & 15;

  // A-fragments from f_s into registers (f_s dead afterwards)
  short8 a[2][4];
  #pragma unroll
  for (int mt = 0; mt < 2; mt++)
    #pragma unroll
    for (int kb = 0; kb < 4; kb++)
      a[mt][kb] = *(const short8*)&F_S((mt << 4) + ln16, (kb << 5) + (quad << 3));
  __syncthreads();

  // stage 1: t = gelu(f @ W1 + b1) -> t_s bf16. Wave w owns N-tiles [w*8, w*8+8).
  {
    const short8* Wp8 = (const short8*)W1p;
    #pragma unroll
    for (int nt = 0; nt < 8; nt++){
      int tile = (w << 3) + nt;
      short8 b[4];
      #pragma unroll
      for (int kb = 0; kb < 4; kb++) b[kb] = Wp8[(size_t)((tile << 2) + kb)*64 + l];
      floatx4 acc0 = {0.f,0.f,0.f,0.f}, acc1 = {0.f,0.f,0.f,0.f};
      #pragma unroll
      for (int kb = 0; kb < 4; kb++){
        acc0 = __builtin_amdgcn_mfma_f32_16x16x32_bf16(a[0][kb], b[kb], acc0, 0, 0, 0);
        acc1 = __builtin_amdgcn_mfma_f32_16x16x32_bf16(a[1][kb], b[kb], acc1, 0, 0, 0);
      }
      int col = (tile << 4) + ln16;
      float bv = b1[col];
      #pragma unroll
      for (int r = 0; r < 4; r++){
        T_S((quad << 2) + r, col)      = f2bf(gelu_f(acc0[r] + bv));
        T_S(16 + (quad << 2) + r, col) = f2bf(gelu_f(acc1[r] + bv));
      }
    }
  }
  __syncthreads();

  // stage 2: f2 = gelu(t @ W2 + b2); out = nf + f2. Wave w owns N-tiles {2w, 2w+1}.
  {
    const short8* Wp8 = (const short8*)W2p;
    int tile0 = (w << 1), tile1 = tile0 + 1;
    floatx4 acc00 = {0.f,0.f,0.f,0.f}, acc01 = {0.f,0.f,0.f,0.f};
    floatx4 acc10 = {0.f,0.f,0.f,0.f}, acc11 = {0.f,0.f,0.f,0.f};
    for (int kb = 0; kb < 16; kb++){
      short8 a0 = *(const short8*)&T_S(ln16,      (kb << 5) + (quad << 3));
      short8 a1 = *(const short8*)&T_S(16 + ln16, (kb << 5) + (quad << 3));
      short8 b0  = Wp8[(size_t)((tile0 << 4) + kb)*64 + l];
      short8 b1v = Wp8[(size_t)((tile1 << 4) + kb)*64 + l];
      acc00 = __builtin_amdgcn_mfma_f32_16x16x32_bf16(a0, b0,  acc00, 0, 0, 0);
      acc01 = __builtin_amdgcn_mfma_f32_16x16x32_bf16(a0, b1v, acc01, 0, 0, 0);
      acc10 = __builtin_amdgcn_mfma_f32_16x16x32_bf16(a1, b0,  acc10, 0, 0, 0);
      acc11 = __builtin_amdgcn_mfma_f32_16x16x32_bf16(a1, b1v, acc11, 0, 0, 0);
    }
    int col0 = (tile0 << 4) + ln16, col1 = (tile1 << 4) + ln16;
    float bv0 = b2[col0], bv1 = b2[col1];
    #pragma unroll
    for (int r = 0; r < 4; r++){
      int n0 = nb + (quad << 2) + r;
      int n1 = n0 + 16;
      if (n0 < N){
        size_t p0 = (size_t)n0*128;
        out[p0 + col0] = nf[p0 + col0] + gelu_f(acc00[r] + bv0);
        out[p0 + col1] = nf[p0 + col1] + gelu_f(acc01[r] + bv1);
      }
      if (n1 < N){
        size_t p1 = (size_t)n1*128;
        out[p1 + col0] = nf[p1 + col0] + gelu_f(acc10[r] + bv0);
        out[p1 + col1] = nf[p1 + col1] + gelu_f(acc11[r] + bv1);
      }
    }
  }
  #undef F_S
  #undef T_S
}

extern "C" void kernel_launch(void* const* d_in, const int* in_sizes, int n_in,
                              void* d_out, int out_size, void* d_ws, size_t ws_size,
                              hipStream_t stream) {
  const float* nf   = (const float*)d_in[0];
  const int*   ei   = (const int*)  d_in[1];
  const float* ln1g = (const float*)d_in[3];
  const float* ln1b = (const float*)d_in[4];
  const float* Wc   = (const float*)d_in[5];
  const float* bc   = (const float*)d_in[6];
  const float* ln2g = (const float*)d_in[7];
  const float* ln2b = (const float*)d_in[8];
  const float* W1   = (const float*)d_in[9];
  const float* b1   = (const float*)d_in[10];
  const float* W2   = (const float*)d_in[11];
  const float* b2   = (const float*)d_in[12];
  float* out = (float*)d_out;

  int N = in_sizes[0] / 128;
  int E = in_sizes[1] / 2;

  char* ws = (char*)d_ws;
  float* agg = (float*)ws;                                       // [N,128] fp32
  unsigned short* hW = (unsigned short*)(ws + (size_t)N*128*4);  // [N,128] bf16
  char* p = ws + (size_t)N*128*4 + (size_t)N*128*2;
  p = (char*)(((size_t)p + 15) & ~(size_t)15);
  int*   incount   = (int*)p;   p += (size_t)N*4;
  float* dinv      = (float*)p; p += (size_t)N*4;
  int*   row_start = (int*)p;   p += (size_t)N*4;
  int*   cursor    = (int*)p;   p += (size_t)N*4;
  int*   eSrc      = (int*)p;   p += (size_t)E*4;
  int*   blkSums   = (int*)p;   p += 2048;
  int*   blkOff    = (int*)p;   p += 2048;
  p = (char*)(((size_t)p + 15) & ~(size_t)15);
  unsigned short* Wcp = (unsigned short*)p; p += (size_t)8*4*64*8*2;     // 32 KB
  unsigned short* W1p = (unsigned short*)p; p += (size_t)32*4*64*8*2;    // 128 KB
  unsigned short* W2p = (unsigned short*)p; p += (size_t)8*16*64*8*2;    // 128 KB

  int SB = (N + 255) / 256;   // 256-node scan chunks, <=512 for N<=131072

  k_init <<<(N+255)/256, 256, 0, stream>>>(incount, N);
  k_count<<<(E+255)/256, 256, 0, stream>>>(ei, incount, E);
  k_scanA<<<SB, 256, 0, stream>>>(incount, row_start, blkSums, N);
  k_scanB<<<1, 512, 0, stream>>>(blkSums, blkOff, SB);
  k_scanC<<<(N+255)/256, 256, 0, stream>>>(incount, blkOff, row_start, cursor, dinv, N);
  k_fill <<<(E+255)/256, 256, 0, stream>>>(ei, cursor, eSrc, E);

  k_pack<<<8,  256, 0, stream>>>(Wc, Wcp, 128, 128);
  k_pack<<<32, 256, 0, stream>>>(W1, W1p, 128, 512);
  k_pack<<<32, 256, 0, stream>>>(W2, W2p, 512, 128);

  k_conv  <<<(N+31)/32, 256, 0, stream>>>(nf, Wcp, ln1g, ln1b, hW, N);
  k_gather<<<(N+3)/4, 256, 0, stream>>>(hW, eSrc, row_start, incount, dinv, agg, N);
  k_ffn   <<<(N+31)/32, 256, 0, stream>>>(nf, agg, bc, ln2g, ln2b, W1p, b1, W2p, b2, out, N);
}